// Round 16
// baseline (1238.204 us; speedup 1.0000x reference)
//
#include <hip/hip_runtime.h>

#define BB 64
#define SS 2048
#define DD 128
#define HH 128

__device__ __forceinline__ float fast_tanh(float x) {
    // tanh(x) = 1 - 2/(e^{2x}+1); exact at +-inf, ~1e-6 rel err
    float e = __expf(2.0f * x);
    return 1.0f - __fdividef(2.0f, e + 1.0f);
}

// 8-lane butterfly ALLreduce, pure DPP: xor1, xor2 (quad_perm), then
// row_half_mirror (lane^7) which acts as xor4 once quads are uniform.
__device__ __forceinline__ float allre8(float v) {
    int a = __builtin_amdgcn_update_dpp(0, __float_as_int(v), 0xB1, 0xF, 0xF, true);  // quad_perm [1,0,3,2]
    v += __int_as_float(a);
    int c = __builtin_amdgcn_update_dpp(0, __float_as_int(v), 0x4E, 0xF, 0xF, true);  // quad_perm [2,3,0,1]
    v += __int_as_float(c);
    int m = __builtin_amdgcn_update_dpp(0, __float_as_int(v), 0x141, 0xF, 0xF, true); // row_half_mirror
    v += __int_as_float(m);
    return v;
}

// LDS-only workgroup barrier: NO vmcnt drain (global ops stay in flight).
__device__ __forceinline__ void wg_sync_lds() {
    asm volatile("s_waitcnt lgkmcnt(0)\n\ts_barrier" ::: "memory");
}

// ---------------------------------------------------------------------------
// Kernel 1: xproj = x @ Wx + b  (register-tiled fp32 GEMM) — unchanged (~45us)
// ---------------------------------------------------------------------------
__global__ __launch_bounds__(256, 2)
void xproj_kernel(const float* __restrict__ x, const float* __restrict__ W,
                  const float* __restrict__ bias, float* __restrict__ out) {
    __shared__ __align__(16) float4 wxs[64 * 32];   // Wx half: [64 k][128 j]
    __shared__ __align__(16) float4 xsw[128 * 16];  // x half:  [128 r][64 k], swizzled
    const int tid = threadIdx.x;
    const int tx  = tid & 15;
    const int ty  = tid >> 4;
    const long row0 = (long)blockIdx.x * 128;

    float acc[8][8];
#pragma unroll
    for (int i = 0; i < 8; ++i)
#pragma unroll
        for (int j = 0; j < 8; ++j) acc[i][j] = 0.f;

    for (int kh = 0; kh < 2; ++kh) {
        {
            const float4* wg = (const float4*)(W + kh * 64 * HH);
#pragma unroll
            for (int i = 0; i < 8; ++i) wxs[tid + i * 256] = wg[tid + i * 256];
        }
        {
#pragma unroll
            for (int i = 0; i < 8; ++i) {
                const int g  = tid + i * 256;
                const int r  = g >> 4;
                const int k4 = g & 15;
                const float4 v = ((const float4*)(x + (row0 + r) * DD + kh * 64))[k4];
                xsw[r * 16 + (k4 ^ ((r >> 3) & 7))] = v;
            }
        }
        __syncthreads();

        for (int k4 = 0; k4 < 16; ++k4) {
            float4 xa[8];
#pragma unroll
            for (int i = 0; i < 8; ++i)
                xa[i] = xsw[(ty * 8 + i) * 16 + (k4 ^ (ty & 7))];
            float4 wa[4][2];
#pragma unroll
            for (int kk = 0; kk < 4; ++kk) {
                wa[kk][0] = wxs[(k4 * 4 + kk) * 32 + tx * 2];
                wa[kk][1] = wxs[(k4 * 4 + kk) * 32 + tx * 2 + 1];
            }
#pragma unroll
            for (int i = 0; i < 8; ++i) {
#pragma unroll
                for (int kk = 0; kk < 4; ++kk) {
                    const float xv = (kk == 0) ? xa[i].x : (kk == 1) ? xa[i].y
                                   : (kk == 2) ? xa[i].z : xa[i].w;
                    acc[i][0] = fmaf(xv, wa[kk][0].x, acc[i][0]);
                    acc[i][1] = fmaf(xv, wa[kk][0].y, acc[i][1]);
                    acc[i][2] = fmaf(xv, wa[kk][0].z, acc[i][2]);
                    acc[i][3] = fmaf(xv, wa[kk][0].w, acc[i][3]);
                    acc[i][4] = fmaf(xv, wa[kk][1].x, acc[i][4]);
                    acc[i][5] = fmaf(xv, wa[kk][1].y, acc[i][5]);
                    acc[i][6] = fmaf(xv, wa[kk][1].z, acc[i][6]);
                    acc[i][7] = fmaf(xv, wa[kk][1].w, acc[i][7]);
                }
            }
        }
        __syncthreads();
    }

    const float4 b0 = ((const float4*)bias)[tx * 2];
    const float4 b1 = ((const float4*)bias)[tx * 2 + 1];
#pragma unroll
    for (int i = 0; i < 8; ++i) {
        const float4 o0 = make_float4(acc[i][0] + b0.x, acc[i][1] + b0.y,
                                      acc[i][2] + b0.z, acc[i][3] + b0.w);
        const float4 o1 = make_float4(acc[i][4] + b1.x, acc[i][5] + b1.y,
                                      acc[i][6] + b1.z, acc[i][7] + b1.w);
        float4* og = (float4*)(out + (row0 + ty * 8 + i) * HH);
        og[tx * 2]     = o0;
        og[tx * 2 + 1] = o1;
    }
}

// ---------------------------------------------------------------------------
// Kernel 2: recurrence v11 — 64 blocks x 256 threads (4 waves), J=4 cols,
// ks=8 (8-lane k-groups). Wh lives in AGPRs (the allocator's stable home —
// R5/R6 proved it never grants VGPR residency; R15 proved VOP3P can't read
// AGPRs), with EXPLICIT per-step v_accvgpr_read shuttles scheduled per-slot
// so they overlap the ds_reads. Eliminates the per-step 64KB L1 Wh stream.
//  - DS/step: 16 staggered b128 reads (<=2-way, free) + 4 masked b32 writes
//  - 8-lane allreduce: 3 pure-DPP stages (xor1, xor2, row_half_mirror)
//  - lanes s8<4 write hb state; s8>=4 store h straight to global (never
//    waited on; barriers are lgkm-only)
//  - xp: 1 float/step/lane, prefetched 2 chunks ahead
// ---------------------------------------------------------------------------

// 64 per-lane Wh floats in AGPRs: wf{slot}{c}{p} = Wh[16*s8+4*((slot+s8)&3)+c][j0+p]
#define DW4(i,c)  float wf##i##c##0, wf##i##c##1, wf##i##c##2, wf##i##c##3;
#define DW16(i)   DW4(i,0) DW4(i,1) DW4(i,2) DW4(i,3)
#define LDW(i,c,p) asm volatile("global_load_dword %0, %1, off" \
    : "=a"(wf##i##c##p) \
    : "v"(Whp + (long)(16 * s8 + 4 * (((i) + s8) & 3) + (c)) * HH + j0 + (p)));
#define LDW4(i,c) LDW(i,c,0) LDW(i,c,1) LDW(i,c,2) LDW(i,c,3)
#define LDW16(i)  LDW4(i,0) LDW4(i,1) LDW4(i,2) LDW4(i,3)

// shuttle one AGPR float to VGPR and accumulate (volatile: keep in-loop)
#define MAC1(i,c,p,hc) { float tw_; \
    asm volatile("v_accvgpr_read_b32 %0, %1" : "=v"(tw_) : "a"(wf##i##c##p)); \
    acc##p = fmaf(hc, tw_, acc##p); }
#define MACC(i,c,hc) MAC1(i,c,0,hc) MAC1(i,c,1,hc) MAC1(i,c,2,hc) MAC1(i,c,3,hc)
#define SLOT(i) { const float4 h4 = hv[ix##i]; \
    MACC(i,0,h4.x) MACC(i,1,h4.y) MACC(i,2,h4.z) MACC(i,3,h4.w) }

__global__ __launch_bounds__(256, 1)
void rnn_kernel(const float* __restrict__ W, float* __restrict__ out) {
    const int CH = 16;
    const int NC = SS / CH;   // 128

    __shared__ __align__(16) float hb[2][HH];   // double-buffered state (1KB)

    const int b   = blockIdx.x;
    const int tid = threadIdx.x;
    const int w   = tid >> 6;
    const int l   = tid & 63;
    const int s8  = l & 7;              // k-slice: k in [16*s8, 16*s8+16)
    const int g8  = l >> 3;             // 0..7 col-group within wave
    const int j0  = w * 32 + g8 * 4;    // 4 cols (j0..j0+3)
    const int cidx = s8 & 3;
    const int col  = j0 + cidx;         // this lane's output column

    // staggered read order: slot i reads float4 idx 4*s8 + ((i+s8)&3)
    const int ix0 = 4 * s8 + ((0 + s8) & 3);
    const int ix1 = 4 * s8 + ((1 + s8) & 3);
    const int ix2 = 4 * s8 + ((2 + s8) & 3);
    const int ix3 = 4 * s8 + ((3 + s8) & 3);

    const float* Whp = W + (long)DD * HH;

    DW16(0) DW16(1) DW16(2) DW16(3)     // 64 AGPR floats
    LDW16(0) LDW16(1) LDW16(2) LDW16(3) // loaded once, acc-dest

    float* const xbase = out + (long)b * SS * HH;

    if (tid < 128) { hb[0][tid] = 0.f; hb[1][tid] = 0.f; }

    // xp for this lane's col: 16 steps/chunk, 2 chunks deep
    float xpc[16], nxt[16];
#pragma unroll
    for (int i = 0; i < 16; ++i) xpc[i] = xbase[(long)i * HH + col];
#pragma unroll
    for (int i = 0; i < 16; ++i) nxt[i] = xbase[(long)(CH + i) * HH + col];

    asm volatile("s_waitcnt vmcnt(0)" ::: "memory");  // Wh + xp resident
    wg_sync_lds();

    for (int c = 0; c < NC; ++c) {
#pragma unroll
        for (int tt = 0; tt < CH; ++tt) {
            const int t = c * CH + tt;
            const float4* hv = (const float4*)hb[(t + 1) & 1];

            float acc0 = 0.f, acc1 = 0.f, acc2 = 0.f, acc3 = 0.f;
            SLOT(0) SLOT(1) SLOT(2) SLOT(3)

            const float r0 = allre8(acc0);
            const float r1 = allre8(acc1);
            const float r2 = allre8(acc2);
            const float r3 = allre8(acc3);
            const float val = (cidx == 0) ? r0 : (cidx == 1) ? r1
                            : (cidx == 2) ? r2 : r3;

            const float h = fast_tanh(val + xpc[tt]);
            if (s8 < 4) hb[t & 1][col] = h;            // state writers
            else        xbase[(long)t * HH + col] = h; // output writers
            wg_sync_lds();                             // lgkm-only
        }
        // rotate xp prefetch: xpc <- nxt, nxt <- chunk c+2
        if (c + 1 < NC) {
#pragma unroll
            for (int i = 0; i < 16; ++i) xpc[i] = nxt[i];
            if (c + 2 < NC) {
                const float* g = xbase + (long)(c + 2) * CH * HH + col;
#pragma unroll
                for (int i = 0; i < 16; ++i) nxt[i] = g[(long)i * HH];
            }
        }
    }

    // final hidden state
    if (tid < 128) {
        out[(long)BB * SS * HH + b * HH + tid] = hb[1][tid];
    }
}

extern "C" void kernel_launch(void* const* d_in, const int* in_sizes, int n_in,
                              void* d_out, int out_size, void* d_ws, size_t ws_size,
                              hipStream_t stream) {
    const float* x    = (const float*)d_in[0];
    const float* W    = (const float*)d_in[1];
    const float* bias = (const float*)d_in[2];
    float* out = (float*)d_out;

    xproj_kernel<<<dim3((BB * SS) / 128), dim3(256), 0, stream>>>(x, W, bias, out);
    rnn_kernel<<<dim3(BB), dim3(256), 0, stream>>>(W, out);
}